// Round 1
// 470.556 us; speedup vs baseline: 1.0761x; 1.0761x over previous
//
#include <hip/hip_runtime.h>

// Splat conv (full true convolution):
//   out[oi, oj] = sum_{di,dj in [0,5)} in[oi-di, oj-dj] * f[di][dj]
// in:  8192 x 8192 fp32, out: 8196 x 8196 fp32 (no bias in forward).
//
// v2: 4x4 output tile per thread (4 rows x one float4), rolling register
// window over 8 input rows. Loads/output drop 2.5x -> 1.0 float4; address
// math amortized 4x; interior fast path has zero bounds checks.

#define IN_H 8192
#define IN_W 8192
#define OUT_H 8196
#define OUT_W 8196
#define NG 2049   // float4 groups per output row
#define NRG 2049  // output row-groups of 4 (2049*4 == 8196)

__global__ __launch_bounds__(256) void splat_conv_kernel(
    const float* __restrict__ in, const float* __restrict__ flt,
    float* __restrict__ out) {
  const int g = blockIdx.x * 64 + threadIdx.x;   // col group (float4)
  const int rg = blockIdx.y * 4 + threadIdx.y;   // output row group
  if (g >= NG || rg >= NRG) return;

  // Filter: uniform loads -> compiler scalarizes into SGPRs.
  float f[25];
#pragma unroll
  for (int i = 0; i < 25; ++i) f[i] = flt[i];

  const int orow = rg * 4;       // first of 4 output rows
  const int c0 = 4 * g - 4;      // base input col (16B aligned)

  float acc[4][4];
#pragma unroll
  for (int k = 0; k < 4; ++k)
#pragma unroll
    for (int m = 0; m < 4; ++m) acc[k][m] = 0.f;

  // Interior: all 8 input rows and 8 input cols in range.
  const bool interior = (g >= 1) & (g <= NG - 2) & (rg >= 1) & (rg <= 2047);

  if (interior) {
    const float* rp = in + (size_t)(orow - 4) * IN_W + c0;
#pragma unroll
    for (int rr = 0; rr < 8; ++rr) {
      const float4 a = *(const float4*)(rp);
      const float4 b = *(const float4*)(rp + 4);
      rp += IN_W;
      float x[8];
      x[0] = a.x; x[1] = a.y; x[2] = a.z; x[3] = a.w;
      x[4] = b.x; x[5] = b.y; x[6] = b.z; x[7] = b.w;
      // input row r = orow-4+rr feeds out row orow+k with di = k+4-rr.
#pragma unroll
      for (int k = 0; k < 4; ++k) {
        const int di = k + 4 - rr;
        if (di < 0 || di > 4) continue;
#pragma unroll
        for (int dj = 0; dj < 5; ++dj) {
          const float w = f[di * 5 + dj];
#pragma unroll
          for (int m = 0; m < 4; ++m) acc[k][m] += x[m + 4 - dj] * w;
        }
      }
    }
  } else {
    const bool lo_ok = (g != 0);
    const bool hi_ok = (g != NG - 1);
#pragma unroll
    for (int rr = 0; rr < 8; ++rr) {
      const int r = orow - 4 + rr;
      float4 a = make_float4(0.f, 0.f, 0.f, 0.f);
      float4 b = make_float4(0.f, 0.f, 0.f, 0.f);
      if (r >= 0 && r < IN_H) {
        const float* rp = in + (size_t)r * IN_W + c0;
        if (lo_ok) a = *(const float4*)(rp);
        if (hi_ok) b = *(const float4*)(rp + 4);
      }
      float x[8];
      x[0] = a.x; x[1] = a.y; x[2] = a.z; x[3] = a.w;
      x[4] = b.x; x[5] = b.y; x[6] = b.z; x[7] = b.w;
#pragma unroll
      for (int k = 0; k < 4; ++k) {
        const int di = k + 4 - rr;
        if (di < 0 || di > 4) continue;
#pragma unroll
        for (int dj = 0; dj < 5; ++dj) {
          const float w = f[di * 5 + dj];
#pragma unroll
          for (int m = 0; m < 4; ++m) acc[k][m] += x[m + 4 - dj] * w;
        }
      }
    }
  }

  // 4 coalesced float4 stores (rows orow..orow+3 all < OUT_H since rg<=2048).
  float* op = out + (size_t)orow * OUT_W + 4 * g;
#pragma unroll
  for (int k = 0; k < 4; ++k) {
    *(float4*)(op) = make_float4(acc[k][0], acc[k][1], acc[k][2], acc[k][3]);
    op += OUT_W;
  }
}

extern "C" void kernel_launch(void* const* d_in, const int* in_sizes, int n_in,
                              void* d_out, int out_size, void* d_ws,
                              size_t ws_size, hipStream_t stream) {
  const float* in = (const float*)d_in[0];
  const float* flt = (const float*)d_in[1];
  // d_in[2] = bias: NOT used by the forward reference.
  float* out = (float*)d_out;

  dim3 block(64, 4);                      // 256 threads
  dim3 grid((NG + 63) / 64, (NRG + 3) / 4);  // 33 x 513
  splat_conv_kernel<<<grid, block, 0, stream>>>(in, flt, out);
}

// Round 2
// 457.509 us; speedup vs baseline: 1.1068x; 1.0285x over previous
//
#include <hip/hip_runtime.h>

// Splat conv (full true convolution):
//   out[oi, oj] = sum_{di,dj in [0,5)} in[oi-di, oj-dj] * f[di][dj]
// in:  8192 x 8192 fp32, out: 8196 x 8196 fp32 (no bias in forward).
//
// v3: 4x4 output tile per thread, ALL 16 input float4 loads hoisted ahead
// of compute (max memory-level parallelism per wave: 16 KB in flight,
// single waitcnt). __launch_bounds__(256,4) lets the compiler keep ~100
// VGPRs (5 waves/SIMD) instead of squeezing to 60 and serializing loads
// into dependent chunks.

#define IN_H 8192
#define IN_W 8192
#define OUT_H 8196
#define OUT_W 8196
#define NG 2049   // float4 groups per output row
#define NRG 2049  // output row-groups of 4 (2049*4 == 8196)

__global__ __launch_bounds__(256, 4) void splat_conv_kernel(
    const float* __restrict__ in, const float* __restrict__ flt,
    float* __restrict__ out) {
  const int g = blockIdx.x * 64 + threadIdx.x;   // col group (float4)
  const int rg = blockIdx.y * 4 + threadIdx.y;   // output row group
  if (g >= NG || rg >= NRG) return;

  // Filter: uniform loads -> compiler scalarizes into SGPRs.
  float f[25];
#pragma unroll
  for (int i = 0; i < 25; ++i) f[i] = flt[i];

  const int orow = rg * 4;       // first of 4 output rows
  const int c0 = 4 * g - 4;      // base input col (16B aligned)

  float acc[4][4];
#pragma unroll
  for (int k = 0; k < 4; ++k)
#pragma unroll
    for (int m = 0; m < 4; ++m) acc[k][m] = 0.f;

  // Interior: all 8 input rows and 8 input cols in range.
  const bool interior = (g >= 1) & (g <= NG - 2) & (rg >= 1) & (rg <= 2047);

  float4 A[8], B[8];
  if (interior) {
    // Issue all 16 loads back-to-back: one vmcnt wait, full MLP.
    const float* rp = in + (size_t)(orow - 4) * IN_W + c0;
#pragma unroll
    for (int rr = 0; rr < 8; ++rr) {
      A[rr] = *(const float4*)(rp);
      B[rr] = *(const float4*)(rp + 4);
      rp += IN_W;
    }
  } else {
    const bool lo_ok = (g != 0);
    const bool hi_ok = (g != NG - 1);
#pragma unroll
    for (int rr = 0; rr < 8; ++rr) {
      const int r = orow - 4 + rr;
      A[rr] = make_float4(0.f, 0.f, 0.f, 0.f);
      B[rr] = make_float4(0.f, 0.f, 0.f, 0.f);
      if (r >= 0 && r < IN_H) {
        const float* rp = in + (size_t)r * IN_W + c0;
        if (lo_ok) A[rr] = *(const float4*)(rp);
        if (hi_ok) B[rr] = *(const float4*)(rp + 4);
      }
    }
  }

#pragma unroll
  for (int rr = 0; rr < 8; ++rr) {
    float x[8];
    x[0] = A[rr].x; x[1] = A[rr].y; x[2] = A[rr].z; x[3] = A[rr].w;
    x[4] = B[rr].x; x[5] = B[rr].y; x[6] = B[rr].z; x[7] = B[rr].w;
    // input row r = orow-4+rr feeds out row orow+k with di = k+4-rr.
#pragma unroll
    for (int k = 0; k < 4; ++k) {
      const int di = k + 4 - rr;
      if (di < 0 || di > 4) continue;
#pragma unroll
      for (int dj = 0; dj < 5; ++dj) {
        const float w = f[di * 5 + dj];
#pragma unroll
        for (int m = 0; m < 4; ++m) acc[k][m] += x[m + 4 - dj] * w;
      }
    }
  }

  // 4 coalesced float4 stores (rows orow..orow+3 all < OUT_H since rg<=2048).
  float* op = out + (size_t)orow * OUT_W + 4 * g;
#pragma unroll
  for (int k = 0; k < 4; ++k) {
    *(float4*)(op) = make_float4(acc[k][0], acc[k][1], acc[k][2], acc[k][3]);
    op += OUT_W;
  }
}

extern "C" void kernel_launch(void* const* d_in, const int* in_sizes, int n_in,
                              void* d_out, int out_size, void* d_ws,
                              size_t ws_size, hipStream_t stream) {
  const float* in = (const float*)d_in[0];
  const float* flt = (const float*)d_in[1];
  // d_in[2] = bias: NOT used by the forward reference.
  float* out = (float*)d_out;

  dim3 block(64, 4);                         // 256 threads
  dim3 grid((NG + 63) / 64, (NRG + 3) / 4);  // 33 x 513
  splat_conv_kernel<<<grid, block, 0, stream>>>(in, flt, out);
}